// Round 1
// baseline (163.448 us; speedup 1.0000x reference)
//
#include <hip/hip_runtime.h>

#define WW 512
#define HH 512
#define NPLANES 64   // B*C = 16*4
#define NCH 4

// sigmoid((x - 0.5) * 10) -- used both for the input transform and the bound
__device__ __forceinline__ float sigf(float x) {
    float z = (x - 0.5f) * 10.0f;
    // exp(-z) = exp2(-z * log2(e)); v_exp_f32 + v_rcp_f32, ~1 ulp each
    float e = __expf(-z);
    return __builtin_amdgcn_rcpf(1.0f + e);
}

__device__ __forceinline__ void load_sig_row(const float* __restrict__ p, float* o) {
    const float4* p4 = reinterpret_cast<const float4*>(p);
    float4 a = p4[0];
    float4 b = p4[1];
    o[0] = sigf(a.x); o[1] = sigf(a.y); o[2] = sigf(a.z); o[3] = sigf(a.w);
    o[4] = sigf(b.x); o[5] = sigf(b.y); o[6] = sigf(b.z); o[7] = sigf(b.w);
}

// Stage 1: per plane (b,c) and per tensor (input/target), compute
//   colsum_partial[tensor][plane][q][c] (q = quarter-plane, summed later)
//   rowsum[tensor][plane][r]
// Grid: 2 tensors * 64 planes * 4 quarters = 512 blocks, 256 threads.
// Each wave handles 32 rows, full width; lane owns 8 contiguous columns.
__global__ __launch_bounds__(256, 4)
void k_stage1(const float* __restrict__ inp, const float* __restrict__ tgt,
              float* __restrict__ colpart, float* __restrict__ rowsum) {
    const int bid    = blockIdx.x;
    const int tensor = bid >> 8;          // 0..1
    const int plane  = (bid >> 2) & 63;   // 0..63
    const int q      = bid & 3;           // 0..3 (128-row quarter)
    const int tid    = threadIdx.x;
    const int wave   = tid >> 6;
    const int lane   = tid & 63;

    const float* __restrict__ base =
        (tensor == 0 ? inp : tgt) + (size_t)plane * (HH * WW);
    const int r0    = q * 128 + wave * 32;
    const int cbase = lane * 8;

    float prev[8], cur[8], nxt[8], cacc[8];
    #pragma unroll
    for (int k = 0; k < 8; ++k) cacc[k] = 0.0f;

    if (r0 == 0) {
        #pragma unroll
        for (int k = 0; k < 8; ++k) prev[k] = 0.0f;  // zero-pad row -1
    } else {
        load_sig_row(base + (size_t)(r0 - 1) * WW + cbase, prev);
    }
    load_sig_row(base + (size_t)r0 * WW + cbase, cur);

    float* __restrict__ rs_out = rowsum + ((size_t)tensor * NPLANES + plane) * HH;

    for (int r = r0; r < r0 + 32; ++r) {
        if (r + 1 < HH) {
            load_sig_row(base + (size_t)(r + 1) * WW + cbase, nxt);
        } else {
            #pragma unroll
            for (int k = 0; k < 8; ++k) nxt[k] = 0.0f;  // zero-pad row H
        }

        // vertical bounds: contribute to column sums (per-lane, no comms)
        #pragma unroll
        for (int k = 0; k < 8; ++k)
            cacc[k] += sigf(fabsf(nxt[k] - prev[k]));

        // horizontal bounds on row r: need +-1 column (cross-lane at edges)
        float lv = __shfl_up(cur[7], 1);
        if (lane == 0)  lv = 0.0f;   // zero-pad col -1
        float rv = __shfl_down(cur[0], 1);
        if (lane == 63) rv = 0.0f;   // zero-pad col W

        float hp = sigf(fabsf(cur[1] - lv));
        #pragma unroll
        for (int k = 1; k < 7; ++k)
            hp += sigf(fabsf(cur[k + 1] - cur[k - 1]));
        hp += sigf(fabsf(rv - cur[6]));

        // wave reduce (64 lanes)
        #pragma unroll
        for (int off = 32; off >= 1; off >>= 1)
            hp += __shfl_xor(hp, off);
        if (lane == 0) rs_out[r] = hp;

        // rotate rolling window
        #pragma unroll
        for (int k = 0; k < 8; ++k) { prev[k] = cur[k]; cur[k] = nxt[k]; }
    }

    // combine column partials across the 4 waves of this block
    __shared__ float cl[4][WW];
    #pragma unroll
    for (int k = 0; k < 8; ++k) cl[wave][cbase + k] = cacc[k];
    __syncthreads();

    float* __restrict__ cp_out =
        colpart + (((size_t)tensor * NPLANES + plane) * 4 + q) * WW;
    for (int c = tid; c < WW; c += 256)
        cp_out[c] = cl[0][c] + cl[1][c] + cl[2][c] + cl[3][c];
}

// logical sobel-source value: S(0)=512*sig(0), S(j)=sum[j-1], 0 outside [0,512)
__device__ __forceinline__ float Sval(const float* s, int j, float s0) {
    if (j < 0 || j >= 512) return 0.0f;
    if (j == 0) return s0;
    return s[j - 1];
}
__device__ __forceinline__ float term(const float* s, int j, float s0) {
    return fabsf(Sval(s, j + 1, s0) - Sval(s, j - 1, s0));
}

// Stage 2: one block per plane (b,c): finalize colsums, sobel+abs+sum both
// directions for both tensors, emit per-plane loss.
__global__ __launch_bounds__(256)
void k_stage2(const float* __restrict__ colpart, const float* __restrict__ rowsum,
              const float* __restrict__ weight, float* __restrict__ plane_loss) {
    __shared__ float cI[WW], cT[WW], rI[WW], rT[WW];
    const int p   = blockIdx.x;   // plane = b*4 + c
    const int tid = threadIdx.x;

    for (int c = tid; c < WW; c += 256) {
        const float* a = colpart + (((size_t)0 * NPLANES + p) * 4) * WW + c;
        const float* b = colpart + (((size_t)1 * NPLANES + p) * 4) * WW + c;
        cI[c] = a[0] + a[WW] + a[2 * WW] + a[3 * WW];
        cT[c] = b[0] + b[WW] + b[2 * WW] + b[3 * WW];
        rI[c] = rowsum[((size_t)0 * NPLANES + p) * HH + c];
        rT[c] = rowsum[((size_t)1 * NPLANES + p) * HH + c];
    }
    __syncthreads();

    // 512 * sigmoid(-5)
    const float s0 = 3.4267396732f;

    float sIx = 0.f, sTx = 0.f, sIy = 0.f, sTy = 0.f;
    for (int j = tid; j < WW; j += 256) {
        sIx += term(cI, j, s0);
        sTx += term(cT, j, s0);
        sIy += term(rI, j, s0);
        sTy += term(rT, j, s0);
    }
    #pragma unroll
    for (int off = 32; off >= 1; off >>= 1) {
        sIx += __shfl_xor(sIx, off);
        sTx += __shfl_xor(sTx, off);
        sIy += __shfl_xor(sIy, off);
        sTy += __shfl_xor(sTy, off);
    }
    __shared__ float red[4][4];
    const int wave = tid >> 6, lane = tid & 63;
    if (lane == 0) {
        red[wave][0] = sIx; red[wave][1] = sTx;
        red[wave][2] = sIy; red[wave][3] = sTy;
    }
    __syncthreads();
    if (tid == 0) {
        float Ix = 0.f, Tx = 0.f, Iy = 0.f, Ty = 0.f;
        for (int w2 = 0; w2 < 4; ++w2) {
            Ix += red[w2][0]; Tx += red[w2][1];
            Iy += red[w2][2]; Ty += red[w2][3];
        }
        Ix *= 0.25f; Tx *= 0.25f; Iy *= 0.25f; Ty *= 0.25f;
        const float wgt = weight[p & (NCH - 1)];
        plane_loss[p] = 0.5f * (fabsf((Ix - Tx) * wgt) + fabsf((Iy - Ty) * wgt));
    }
}

// Stage 3: mean over 64 plane losses
__global__ void k_stage3(const float* __restrict__ plane_loss, float* __restrict__ out) {
    const int lane = threadIdx.x;
    float v = plane_loss[lane];
    #pragma unroll
    for (int off = 32; off >= 1; off >>= 1)
        v += __shfl_xor(v, off);
    if (lane == 0) out[0] = v * (1.0f / 64.0f);
}

extern "C" void kernel_launch(void* const* d_in, const int* in_sizes, int n_in,
                              void* d_out, int out_size, void* d_ws, size_t ws_size,
                              hipStream_t stream) {
    const float* inp = (const float*)d_in[0];
    const float* tgt = (const float*)d_in[1];
    const float* wgt = (const float*)d_in[2];
    float* ws = (float*)d_ws;

    // ws layout (floats):
    float* colpart = ws;                       // [2][64][4][512] = 262144
    float* rowsum  = ws + 262144;              // [2][64][512]    = 65536
    float* ploss   = ws + 262144 + 65536;      // [64]

    k_stage1<<<512, 256, 0, stream>>>(inp, tgt, colpart, rowsum);
    k_stage2<<<64, 256, 0, stream>>>(colpart, rowsum, wgt, ploss);
    k_stage3<<<1, 64, 0, stream>>>(ploss, (float*)d_out);
}